// Round 5
// baseline (196.520 us; speedup 1.0000x reference)
//
#include <hip/hip_runtime.h>
#include <math.h>

// (N,C,D,H,W)=(2,32,48,48,48), K=3, T=8. All fp32 in/out (verified R5).
// R15 = R14 bugfix. R14's staging assigned entries e=tid+i*512 but each
// thread writes only its channel-half (half*4 offset) -> half of every
// entry's 8 bytes was never written (NaN). Fix: every thread stages entries
// e=v+i*256 (v=tid&255, 6 entries), writing its half's 4B of ALL entries.
// Structure: 2 threads/voxel (512-thr blocks). VGPR>64 caps residency at 16
// waves/CU; grid 864x8=6912 waves oversubscribes 4096 capacity -> CUs stay
// at 16 waves/CU (vs R13's 13.5) and per-wave dependent chains halve.
#define NB   2
#define CH   32
#define DHW  (48*48*48)
#define TT   8
#define EPSF 1e-6f

#define TILE_N   1521            // 13*13*9 halo entries (1 entry = 4 ch fp16, 8B)
#define TILE_WSTR 1522           // entries per buffer (+1 zero pad)
#define TILE_BYTES (TILE_WSTR*8) // 12176
#define GROUPS   8               // 32 ch / 4 per group

// LDS layout (bytes): tokens [0,16384) = 256*64 ; tile 2 bufs [16384,40736)
// cbuf aliases [0,36864) = 256 rows * 36 floats (post-loop only)
#define TOK_OFF  0
#define TOK_STR  64
#define TILE_OFF 16384
#define SMEM_SZ  (16384 + 2*TILE_BYTES)   // 40736

// ws layout (float idx): Bt f16 [0,4096) floats (=8192 ushort), wf 4096, bf 4480, bm 4492
#define WS_BT_F 0
#define WS_WF   4096
#define WS_BF   4480
#define WS_BM   4492

typedef __attribute__((ext_vector_type(8))) short short8;
typedef __attribute__((ext_vector_type(8))) _Float16 half8;
typedef __attribute__((ext_vector_type(4))) float floatx4;
typedef __attribute__((ext_vector_type(2))) _Float16 h2;

__device__ __forceinline__ h2 pkrtz(float a, float b) {
    return __builtin_bit_cast(h2, __builtin_amdgcn_cvt_pkrtz(a, b));
}
__device__ __forceinline__ unsigned pkrtz_u(float a, float b) {
    return __builtin_bit_cast(unsigned, __builtin_amdgcn_cvt_pkrtz(a, b));
}

__global__ __launch_bounds__(256) void prep_kernel(
        const float* __restrict__ w_field,
        const float* __restrict__ b_field,
        const float* __restrict__ gates,
        const float* __restrict__ w_mix,
        const float* __restrict__ b_mix,
        float* __restrict__ ws) {
    int i = blockIdx.x * 256 + threadIdx.x;    // grid 32*256 = 8192
    // Bt[o][k] f16 (RNE), k = c*8 + t, value = sigmoid(gates[t]) * w_mix[o, t*32+c]
    {
        int o = i >> 8, k = i & 255, c = k >> 3, t = k & 7;
        float sg = 1.0f / (1.0f + expf(-gates[t]));
        _Float16 hv = (_Float16)(sg * w_mix[o * 256 + t * 32 + c]);
        ((unsigned short*)(ws + WS_BT_F))[o * 256 + k] = __builtin_bit_cast(unsigned short, hv);
    }
    if (i < 384) { int c = i / 12, o = i - c * 12; ws[WS_WF + i] = w_field[o * 32 + c]; }
    if (i < 12)  ws[WS_BF + i] = b_field[i];
    if (i < 32)  ws[WS_BM + i] = b_mix[i];
}

__global__ __launch_bounds__(512) void geo_main(
        const float* __restrict__ x,
        const float* __restrict__ ws,
        float* __restrict__ out) {
    __shared__ __align__(16) char smem[SMEM_SZ];
    char* tokb  = smem + TOK_OFF;
    char* tileb = smem + TILE_OFF;             // 2 buffers of TILE_BYTES
    float* cbuf = (float*)smem;                // alias, post-loop only

    const int tid  = threadIdx.x;              // 0..511
    const int v    = tid & 255;                // voxel id within block
    const int half = tid >> 8;                 // 0: ch pair lo, 1: ch pair hi
    // XCD-locality swizzle: chunk c = blockIdx&7 gets lin in [108c,108(c+1)).
    const int lin = (blockIdx.x & 7) * 108 + (blockIdx.x >> 3);
    const int bx = lin % 6, by = (lin / 6) % 6, bz = (lin / 36) % 12, n = lin / 432;
    const int lx = v & 7, ly = (v >> 3) & 7, lz = v >> 6;
    const int w = bx * 8 + lx, h = by * 8 + ly, d = bz * 4 + lz;
    const int xlo = bx * 8 - 2, ylo = by * 8 - 2, zlo = bz * 4 - 2;
    const int lane = tid & 63, wv = tid >> 6;  // wave 0..7

    const float* xn = x + (size_t)n * CH * DHW;

    // ---- channel-invariant halo-load offsets (6 entries per voxel-slot) ----
    int goff[6];
#pragma unroll
    for (int i = 0; i < 6; ++i) {
        int e  = v + i * 256;
        int ee = (e < TILE_N) ? e : 0;
        int tz = ee / 169; int r0 = ee - tz * 169;
        int ty = r0 / 13;  int tx = r0 - ty * 13;
        int zg = min(max(zlo + tz, 0), 47);
        int yg = min(max(ylo + ty, 0), 47);
        int xg = min(max(xlo + tx, 0), 47);
        goff[i] = (zg * 48 + yg) * 48 + xg;
    }

    // ---- phase A: f[12] = w_field @ x(:,pos) + b_field (dup across halves) ----
    const int pos = (d * 48 + h) * 48 + w;
    float f[12];
#pragma unroll
    for (int o = 0; o < 12; ++o) f[o] = ws[WS_BF + o];
    for (int c = 0; c < CH; ++c) {
        float xv = xn[c * DHW + pos];
        const float* wf = ws + WS_WF + c * 12;
#pragma unroll
        for (int o = 0; o < 12; ++o) f[o] = fmaf(wf[o], xv, f[o]);
    }

    // ---- per-voxel sample parameters (byte offsets into tile) ----
    h2 fx2[6], fy2[6], fz2[6];
    int a00[6], a01[6], a10[6], a11[6];
    float uxk[3], uyk[3], uzk[3], irk[3], ir2k[3];
    const float cscale = 48.0f / (48.0f + EPSF);
#pragma unroll
    for (int k = 0; k < 3; ++k) {
        float vx = f[4*k], vy = f[4*k+1], vz = f[4*k+2], s = f[4*k+3];
        float inv = 1.0f / sqrtf(vx*vx + vy*vy + vz*vz + EPSF);
        float ux = vx * inv, uy = vy * inv, uz = vz * inv;
        float r  = 0.5f + 1.5f / (1.0f + expf(-s));
        uxk[k] = ux; uyk[k] = uy; uzk[k] = uz;
        float ir = 1.0f / (r + EPSF); irk[k] = ir; ir2k[k] = ir * ir;
#pragma unroll
        for (int sgn = 0; sgn < 2; ++sgn) {
            int   si = 2 * k + sgn;
            float sf = sgn ? -1.0f : 1.0f;
            float txr = (float)w + sf * r * ux * cscale;
            float tyr = (float)h + sf * r * uy * cscale;
            float tzr = (float)d + sf * r * uz * cscale;
            float cx = fabsf(txr + 0.5f); float ix = fminf(cx, 96.0f - cx) - 0.5f;
            float cy = fabsf(tyr + 0.5f); float iy = fminf(cy, 96.0f - cy) - 0.5f;
            float cz = fabsf(tzr + 0.5f); float iz = fminf(cz, 96.0f - cz) - 0.5f;
            float x0f = floorf(ix), y0f = floorf(iy), z0f = floorf(iz);
            float fx = ix - x0f, fy = iy - y0f, fz = iz - z0f;
            int x0 = min(max((int)x0f, 0), 47); int x1 = min(x0 + 1, 47);
            int y0 = min(max((int)y0f, 0), 47); int y1 = min(y0 + 1, 47);
            int z0 = min(max((int)z0f, 0), 47); int z1 = min(z0 + 1, 47);
            float fxe = (x1 == x0) ? 0.0f : fx;  // reference's clipped-x1 semantics
            _Float16 hx = (_Float16)fxe, hy = (_Float16)fy, hz = (_Float16)fz;
            fx2[si] = (h2){hx, hx}; fy2[si] = (h2){hy, hy}; fz2[si] = (h2){hz, hz};
            int lz0 = z0 - zlo, lz1 = z1 - zlo;
            int ly0 = y0 - ylo, ly1 = y1 - ylo;
            int lx0 = x0 - xlo;
            a00[si] = (((lz0 * 13 + ly0) * 13 + lx0)) * 8;
            a01[si] = (((lz0 * 13 + ly1) * 13 + lx0)) * 8;
            a10[si] = (((lz1 * 13 + ly0) * 13 + lx0)) * 8;
            a11[si] = (((lz1 * 13 + ly1) * 13 + lx0)) * 8;
        }
    }

    // ---- stage group 0 tile: each thread writes its half's 4B of 6 entries ----
    if (tid == 0) {
        *(float*)(tileb + TILE_N * 8) = 0.f; *(float*)(tileb + TILE_N * 8 + 4) = 0.f;
        *(float*)(tileb + TILE_BYTES + TILE_N * 8) = 0.f;
        *(float*)(tileb + TILE_BYTES + TILE_N * 8 + 4) = 0.f;
    }
    {
        const float* xc = xn + (2 * half) * DHW;
        float ld[12];
#pragma unroll
        for (int i = 0; i < 6; ++i) { ld[i] = xc[goff[i]]; ld[6 + i] = xc[DHW + goff[i]]; }
#pragma unroll
        for (int i = 0; i < 6; ++i) {
            int e = v + i * 256;
            if (e < TILE_N)
                *(h2*)(tileb + e * 8 + half * 4) = pkrtz(ld[i], ld[6 + i]);
        }
    }
    __syncthreads();

    floatx4 acc[2][2];
#pragma unroll
    for (int mt = 0; mt < 2; ++mt)
#pragma unroll
        for (int nt = 0; nt < 2; ++nt) acc[mt][nt] = (floatx4){0.f, 0.f, 0.f, 0.f};

    const int selfb = (((lz + 2) * 13 + (ly + 2)) * 13 + (lx + 2)) * 8;
    const unsigned short* bt = (const unsigned short*)(ws + WS_BT_F);
    const int tokq = (v >> 3) & 3;             // token-quadrant swizzle key (voxel-keyed)
    const int qm = lane >> 4, nlo = lane & 15;

    // B-fragment rolling prefetch (hidden under trilinear compute)
    short8 bc0 = *(const short8*)(bt + (nlo * 256 + qm * 8));
    short8 bc1 = *(const short8*)(bt + ((nlo + 16) * 256 + qm * 8));

    for (int g = 0; g < GROUPS; ++g) {
        const int rb = (g & 1);
        const int wb = rb ^ 1;
        float nld[12];
        short8 bn0 = bc0, bn1 = bc1;
        if (g < GROUPS - 1) {
            const float* xc = xn + ((g + 1) * 4 + 2 * half) * DHW;
#pragma unroll
            for (int i = 0; i < 6; ++i) { nld[i] = xc[goff[i]]; nld[6 + i] = xc[DHW + goff[i]]; }
            bn0 = *(const short8*)(bt + (nlo * 256 + (g + 1) * 32 + qm * 8));
            bn1 = *(const short8*)(bt + ((nlo + 16) * 256 + (g + 1) * 32 + qm * 8));
        }
        // ---- trilinear on this thread's h2 channel pair ----
        const char* tb = tileb + rb * TILE_BYTES + half * 4;
        h2 s2 = *(const h2*)(tb + selfb);
        h2 v2[6];
#pragma unroll
        for (int si = 0; si < 6; ++si) {
            int b00 = a00[si], b01 = a01[si], b10 = a10[si], b11 = a11[si];
            h2 v000 = *(const h2*)(tb + b00), v001 = *(const h2*)(tb + b00 + 8);
            h2 v010 = *(const h2*)(tb + b01), v011 = *(const h2*)(tb + b01 + 8);
            h2 v100 = *(const h2*)(tb + b10), v101 = *(const h2*)(tb + b10 + 8);
            h2 v110 = *(const h2*)(tb + b11), v111 = *(const h2*)(tb + b11 + 8);
            h2 fx = fx2[si], fy = fy2[si], fz = fz2[si];
            h2 c00 = v000 + fx * (v001 - v000);
            h2 c01 = v010 + fx * (v011 - v010);
            h2 c10 = v100 + fx * (v101 - v100);
            h2 c11 = v110 + fx * (v111 - v110);
            h2 c0  = c00 + fy * (c01 - c00);
            h2 c1  = c10 + fy * (c11 - c10);
            v2[si] = c0 + fz * (c1 - c0);
        }
        // ---- token assembly: this thread's 2 channels ----
#pragma unroll
        for (int sub = 0; sub < 2; ++sub) {
            float xv = sub ? (float)s2.y : (float)s2.x;
            float val[6];
#pragma unroll
            for (int si = 0; si < 6; ++si)
                val[si] = sub ? (float)v2[si].y : (float)v2[si].x;
            float t1, t2, t3, gx, gy, gz, l;
            {
                float sp, sm, d1;
                sp = val[0]; sm = val[1]; t1 = 0.5f * (sp + sm);
                d1 = 0.5f * (sp - sm) * irk[0];
                gx = uxk[0] * d1; gy = uyk[0] * d1; gz = uzk[0] * d1;
                l  = (sp + sm - 2.0f * xv) * ir2k[0];
                sp = val[2]; sm = val[3]; t2 = 0.5f * (sp + sm);
                d1 = 0.5f * (sp - sm) * irk[1];
                gx = fmaf(uxk[1], d1, gx); gy = fmaf(uyk[1], d1, gy); gz = fmaf(uzk[1], d1, gz);
                l  = fmaf(sp + sm - 2.0f * xv, ir2k[1], l);
                sp = val[4]; sm = val[5]; t3 = 0.5f * (sp + sm);
                d1 = 0.5f * (sp - sm) * irk[2];
                gx = fmaf(uxk[2], d1, gx); gy = fmaf(uyk[2], d1, gy); gz = fmaf(uzk[2], d1, gz);
                l  = fmaf(sp + sm - 2.0f * xv, ir2k[2], l);
            }
            uint4 tw;
            tw.x = pkrtz_u(xv, t1);
            tw.y = pkrtz_u(t2, t3);
            tw.z = pkrtz_u(gx, gy);
            tw.w = pkrtz_u(gz, l * (1.0f / 3.0f));
            int cg = 2 * half + sub;
            int qe = cg ^ tokq;                // bank-conflict-free token write
            *(uint4*)(tokb + v * TOK_STR + qe * 16) = tw;
        }
        __syncthreads();   // tokens complete (cross-wave rows)

        // ---- MFMA: K-chunk g, 8 waves x 2 row-blocks ----
        {
            half8 hb0 = __builtin_bit_cast(half8, bc0);
            half8 hb1 = __builtin_bit_cast(half8, bc1);
#pragma unroll
            for (int mt = 0; mt < 2; ++mt) {
                int row = wv * 32 + mt * 16 + nlo;
                int qe  = qm ^ ((row >> 3) & 3);
                half8 a = __builtin_bit_cast(half8,
                          *(const short8*)(tokb + row * TOK_STR + qe * 16));
                acc[mt][0] = __builtin_amdgcn_mfma_f32_16x16x32_f16(a, hb0, acc[mt][0], 0, 0, 0);
                acc[mt][1] = __builtin_amdgcn_mfma_f32_16x16x32_f16(a, hb1, acc[mt][1], 0, 0, 0);
            }
        }
        bc0 = bn0; bc1 = bn1;

        // ---- stage g+1 into the other tile buffer ----
        if (g < GROUPS - 1) {
#pragma unroll
            for (int i = 0; i < 6; ++i) {
                int e = v + i * 256;
                if (e < TILE_N)
                    *(h2*)(tileb + wb * TILE_BYTES + e * 8 + half * 4) = pkrtz(nld[i], nld[6 + i]);
            }
        }
        __syncthreads();   // tile[wb] staged; token reads done
    }

    // ---- C writeback via LDS (col-swizzled, conflict-free) ----
    {
#pragma unroll
        for (int mt = 0; mt < 2; ++mt)
#pragma unroll
            for (int nt = 0; nt < 2; ++nt)
#pragma unroll
                for (int r = 0; r < 4; ++r) {
                    int vr = wv * 32 + mt * 16 + qm * 4 + r;
                    int col = nt * 16 + nlo;
                    cbuf[vr * 36 + (col ^ (vr & 31))] = acc[mt][nt][r];
                }
    }
    __syncthreads();

    // ---- epilogue: out = x + delta + b_mix (each thread: 16 channels) ----
    const float* dr = cbuf + v * 36;
    float* on = out + (size_t)n * CH * DHW;
#pragma unroll
    for (int o = 0; o < 16; ++o) {
        int oo = half * 16 + o;
        __builtin_nontemporal_store(
            xn[oo * DHW + pos] + dr[oo ^ (v & 31)] + ws[WS_BM + oo],
            on + oo * DHW + pos);
    }
}

extern "C" void kernel_launch(void* const* d_in, const int* in_sizes, int n_in,
                              void* d_out, int out_size, void* d_ws, size_t ws_size,
                              hipStream_t stream) {
    const float *x = (const float*)d_in[0], *w_field = (const float*)d_in[1],
                *b_field = (const float*)d_in[2], *gates = (const float*)d_in[3],
                *w_mix = (const float*)d_in[4], *b_mix = (const float*)d_in[5];
    for (int i = 0; i < n_in; ++i) {
        switch (in_sizes[i]) {
            case NB * CH * DHW: x       = (const float*)d_in[i]; break;
            case 12 * CH:       w_field = (const float*)d_in[i]; break;
            case 12:            b_field = (const float*)d_in[i]; break;
            case TT:            gates   = (const float*)d_in[i]; break;
            case CH * TT * CH:  w_mix   = (const float*)d_in[i]; break;
            case CH:            b_mix   = (const float*)d_in[i]; break;
            default: break;
        }
    }
    float* ws = (float*)d_ws;
    prep_kernel<<<32, 256, 0, stream>>>(w_field, b_field, gates, w_mix, b_mix, ws);
    geo_main<<<864, 512, 0, stream>>>(x, ws, (float*)d_out);
}